// Round 4
// baseline (2136.582 us; speedup 1.0000x reference)
//
#include <hip/hip_runtime.h>

constexpr int Bn = 8, Nn = 1024, Cn = 768, Hn = 12, Dn = 64;

__device__ __forceinline__ unsigned toOrd(float f) {
  unsigned u = __float_as_uint(f);
  return (u & 0x80000000u) ? ~u : (u | 0x80000000u);
}

// ---- wave64 reductions via DPP (pure VALU: no LDS, no SALU hazards) --------
// row_shr:1/2/4/8 -> each row16's lane15 holds row sum; row_bcast:15 (rows 1,3)
// + row_bcast:31 (rows 2,3) -> lane63 holds wave total.  [canonical GCN seq]
__device__ __forceinline__ int wave_sum_i32(int x) {
  x += __builtin_amdgcn_update_dpp(0, x, 0x111, 0xF, 0xF, false);
  x += __builtin_amdgcn_update_dpp(0, x, 0x112, 0xF, 0xF, false);
  x += __builtin_amdgcn_update_dpp(0, x, 0x114, 0xF, 0xF, false);
  x += __builtin_amdgcn_update_dpp(0, x, 0x118, 0xF, 0xF, false);
  x += __builtin_amdgcn_update_dpp(0, x, 0x142, 0xA, 0xF, false);
  x += __builtin_amdgcn_update_dpp(0, x, 0x143, 0xC, 0xF, false);
  return __builtin_amdgcn_readlane(x, 63);
}
__device__ __forceinline__ float wave_sum_f32(float x) {
  int xi = __float_as_int(x);
  x += __int_as_float(__builtin_amdgcn_update_dpp(0, xi, 0x111, 0xF, 0xF, false)); xi = __float_as_int(x);
  x += __int_as_float(__builtin_amdgcn_update_dpp(0, xi, 0x112, 0xF, 0xF, false)); xi = __float_as_int(x);
  x += __int_as_float(__builtin_amdgcn_update_dpp(0, xi, 0x114, 0xF, 0xF, false)); xi = __float_as_int(x);
  x += __int_as_float(__builtin_amdgcn_update_dpp(0, xi, 0x118, 0xF, 0xF, false)); xi = __float_as_int(x);
  x += __int_as_float(__builtin_amdgcn_update_dpp(0, xi, 0x142, 0xA, 0xF, false)); xi = __float_as_int(x);
  x += __int_as_float(__builtin_amdgcn_update_dpp(0, xi, 0x143, 0xC, 0xF, false));
  return __int_as_float(__builtin_amdgcn_readlane(__float_as_int(x), 63));
}
__device__ __forceinline__ float wave_max_f32(float x) {
  int xi = __float_as_int(x);   // old = self: identity under max for masked lanes
  x = fmaxf(x, __int_as_float(__builtin_amdgcn_update_dpp(xi, xi, 0x111, 0xF, 0xF, false))); xi = __float_as_int(x);
  x = fmaxf(x, __int_as_float(__builtin_amdgcn_update_dpp(xi, xi, 0x112, 0xF, 0xF, false))); xi = __float_as_int(x);
  x = fmaxf(x, __int_as_float(__builtin_amdgcn_update_dpp(xi, xi, 0x114, 0xF, 0xF, false))); xi = __float_as_int(x);
  x = fmaxf(x, __int_as_float(__builtin_amdgcn_update_dpp(xi, xi, 0x118, 0xF, 0xF, false))); xi = __float_as_int(x);
  x = fmaxf(x, __int_as_float(__builtin_amdgcn_update_dpp(xi, xi, 0x142, 0xA, 0xF, false))); xi = __float_as_int(x);
  x = fmaxf(x, __int_as_float(__builtin_amdgcn_update_dpp(xi, xi, 0x143, 0xC, 0xF, false)));
  return __int_as_float(__builtin_amdgcn_readlane(__float_as_int(x), 63));
}
__device__ __forceinline__ unsigned wave_min_u32(unsigned x) {
  int xi = (int)x;              // old = self: identity under min for masked lanes
  x = min(x, (unsigned)__builtin_amdgcn_update_dpp(xi, xi, 0x111, 0xF, 0xF, false)); xi = (int)x;
  x = min(x, (unsigned)__builtin_amdgcn_update_dpp(xi, xi, 0x112, 0xF, 0xF, false)); xi = (int)x;
  x = min(x, (unsigned)__builtin_amdgcn_update_dpp(xi, xi, 0x114, 0xF, 0xF, false)); xi = (int)x;
  x = min(x, (unsigned)__builtin_amdgcn_update_dpp(xi, xi, 0x118, 0xF, 0xF, false)); xi = (int)x;
  x = min(x, (unsigned)__builtin_amdgcn_update_dpp(xi, xi, 0x142, 0xA, 0xF, false)); xi = (int)x;
  x = min(x, (unsigned)__builtin_amdgcn_update_dpp(xi, xi, 0x143, 0xC, 0xF, false));
  return (unsigned)__builtin_amdgcn_readlane((int)x, 63);
}

// ---------------- QKV GEMM (128x128 tile, 8x8 acc): qkv = x@W^T + b ---------
__global__ __launch_bounds__(256, 4) void qkv_gemm(
    const float* __restrict__ X, const float* __restrict__ Wm,
    const float* __restrict__ bias,
    float* __restrict__ qb, float* __restrict__ kb, float* __restrict__ vb)
{
  constexpr int BK = 16, LD = 132;
  __shared__ float As[BK][LD];
  __shared__ float Bs[BK][LD];
  int t = threadIdx.x;
  int mt = blockIdx.x & 63;         // 64 m-tiles
  int nt = blockIdx.x >> 6;         // 18 n-tiles
  int m0 = mt * 128, n0 = nt * 128;
  int sr = t >> 1;                  // staging row 0..127
  int sk = (t & 1) * 8;             // staging k 0 or 8
  const float* Ap = X  + (size_t)(m0 + sr) * Cn + sk;
  const float* Bp = Wm + (size_t)(n0 + sr) * Cn + sk;
  int tm = t >> 4, tn = t & 15;
  float acc[8][8] = {};
  for (int k0 = 0; k0 < Cn; k0 += BK) {
    float4 a0 = *(const float4*)(Ap + k0);
    float4 a1 = *(const float4*)(Ap + k0 + 4);
    float4 b0 = *(const float4*)(Bp + k0);
    float4 b1 = *(const float4*)(Bp + k0 + 4);
    __syncthreads();
    As[sk+0][sr]=a0.x; As[sk+1][sr]=a0.y; As[sk+2][sr]=a0.z; As[sk+3][sr]=a0.w;
    As[sk+4][sr]=a1.x; As[sk+5][sr]=a1.y; As[sk+6][sr]=a1.z; As[sk+7][sr]=a1.w;
    Bs[sk+0][sr]=b0.x; Bs[sk+1][sr]=b0.y; Bs[sk+2][sr]=b0.z; Bs[sk+3][sr]=b0.w;
    Bs[sk+4][sr]=b1.x; Bs[sk+5][sr]=b1.y; Bs[sk+6][sr]=b1.z; Bs[sk+7][sr]=b1.w;
    __syncthreads();
#pragma unroll
    for (int kk = 0; kk < BK; ++kk) {
      float4 x0 = *(const float4*)(&As[kk][tm*8]);
      float4 x1 = *(const float4*)(&As[kk][tm*8+4]);
      float4 y0 = *(const float4*)(&Bs[kk][tn*8]);
      float4 y1 = *(const float4*)(&Bs[kk][tn*8+4]);
      float av[8] = {x0.x,x0.y,x0.z,x0.w,x1.x,x1.y,x1.z,x1.w};
      float bv[8] = {y0.x,y0.y,y0.z,y0.w,y1.x,y1.y,y1.z,y1.w};
#pragma unroll
      for (int i = 0; i < 8; ++i)
#pragma unroll
        for (int j = 0; j < 8; ++j) acc[i][j] = fmaf(av[i], bv[j], acc[i][j]);
    }
  }
  // epilogue: scatter to q/k/v (B,H,N,d); 64|c-groups so h uniform per float4
  int c0 = n0 + tn*8;
  int which = c0 / Cn;
  int rem0 = c0 - which*Cn;
  float* dst = which == 0 ? qb : (which == 1 ? kb : vb);
  float sc = which == 0 ? 0.125f : 1.0f;   // q pre-scaled by d^-0.5
  float4 bs0 = *(const float4*)(bias + c0);
  float4 bs1 = *(const float4*)(bias + c0 + 4);
  int h0 = rem0 >> 6, dd0 = rem0 & 63;
#pragma unroll
  for (int i = 0; i < 8; ++i) {
    int mrow = m0 + tm*8 + i;
    int bbi = mrow >> 10, n = mrow & 1023;
    size_t base = (((size_t)(bbi*Hn + h0))*Nn + n)*Dn + dd0;
    float4 o0, o1;
    o0.x=(acc[i][0]+bs0.x)*sc; o0.y=(acc[i][1]+bs0.y)*sc; o0.z=(acc[i][2]+bs0.z)*sc; o0.w=(acc[i][3]+bs0.w)*sc;
    o1.x=(acc[i][4]+bs1.x)*sc; o1.y=(acc[i][5]+bs1.y)*sc; o1.z=(acc[i][6]+bs1.z)*sc; o1.w=(acc[i][7]+bs1.w)*sc;
    *(float4*)(dst + base)     = o0;
    *(float4*)(dst + base + 4) = o1;
  }
}

// ---------------- Proj GEMM (128x128 tile, 8x8 acc): out = att@W^T + b ------
__global__ __launch_bounds__(256, 4) void proj_gemm(
    const float* __restrict__ X, const float* __restrict__ Wm,
    const float* __restrict__ bias, float* __restrict__ Out)
{
  constexpr int BK = 16, LD = 132;
  __shared__ float As[BK][LD];
  __shared__ float Bs[BK][LD];
  int t = threadIdx.x;
  int mt = blockIdx.x & 63;
  int nt = blockIdx.x >> 6;         // 6 n-tiles
  int m0 = mt * 128, n0 = nt * 128;
  int sr = t >> 1;
  int sk = (t & 1) * 8;
  const float* Ap = X  + (size_t)(m0 + sr) * Cn + sk;
  const float* Bp = Wm + (size_t)(n0 + sr) * Cn + sk;
  int tm = t >> 4, tn = t & 15;
  float acc[8][8] = {};
  for (int k0 = 0; k0 < Cn; k0 += BK) {
    float4 a0 = *(const float4*)(Ap + k0);
    float4 a1 = *(const float4*)(Ap + k0 + 4);
    float4 b0 = *(const float4*)(Bp + k0);
    float4 b1 = *(const float4*)(Bp + k0 + 4);
    __syncthreads();
    As[sk+0][sr]=a0.x; As[sk+1][sr]=a0.y; As[sk+2][sr]=a0.z; As[sk+3][sr]=a0.w;
    As[sk+4][sr]=a1.x; As[sk+5][sr]=a1.y; As[sk+6][sr]=a1.z; As[sk+7][sr]=a1.w;
    Bs[sk+0][sr]=b0.x; Bs[sk+1][sr]=b0.y; Bs[sk+2][sr]=b0.z; Bs[sk+3][sr]=b0.w;
    Bs[sk+4][sr]=b1.x; Bs[sk+5][sr]=b1.y; Bs[sk+6][sr]=b1.z; Bs[sk+7][sr]=b1.w;
    __syncthreads();
#pragma unroll
    for (int kk = 0; kk < BK; ++kk) {
      float4 x0 = *(const float4*)(&As[kk][tm*8]);
      float4 x1 = *(const float4*)(&As[kk][tm*8+4]);
      float4 y0 = *(const float4*)(&Bs[kk][tn*8]);
      float4 y1 = *(const float4*)(&Bs[kk][tn*8+4]);
      float av[8] = {x0.x,x0.y,x0.z,x0.w,x1.x,x1.y,x1.z,x1.w};
      float bv[8] = {y0.x,y0.y,y0.z,y0.w,y1.x,y1.y,y1.z,y1.w};
#pragma unroll
      for (int i = 0; i < 8; ++i)
#pragma unroll
        for (int j = 0; j < 8; ++j) acc[i][j] = fmaf(av[i], bv[j], acc[i][j]);
    }
  }
  int c0 = n0 + tn*8;
  float4 bs0 = *(const float4*)(bias + c0);
  float4 bs1 = *(const float4*)(bias + c0 + 4);
#pragma unroll
  for (int i = 0; i < 8; ++i) {
    int mrow = m0 + tm*8 + i;
    float4 o0, o1;
    o0.x=acc[i][0]+bs0.x; o0.y=acc[i][1]+bs0.y; o0.z=acc[i][2]+bs0.z; o0.w=acc[i][3]+bs0.w;
    o1.x=acc[i][4]+bs1.x; o1.y=acc[i][5]+bs1.y; o1.z=acc[i][6]+bs1.z; o1.w=acc[i][7]+bs1.w;
    *(float4*)(Out + (size_t)mrow*Cn + c0)     = o0;
    *(float4*)(Out + (size_t)mrow*Cn + c0 + 4) = o1;
  }
}

// ---------------- Attention: scores + DPP-bisect exact top-k + softmax + PV -
// One block = (b,h) x 8 q-rows, 512 threads = 8 waves; wave w owns row w.
// LDS = 34 KB -> 4 blocks/CU (32 waves/CU).
__global__ __launch_bounds__(512, 8) void attn_kernel(
    const float* __restrict__ qB, const float* __restrict__ kB,
    const float* __restrict__ vB, const int* __restrict__ kptr,
    float* __restrict__ out)
{
  constexpr int G = 8, CAP = 128;
  __shared__ float  Ws[G][1024];     // scores; tail of own row reused for pairs
  __shared__ float4 Qs[G][16];       // 2 KB

  int t = threadIdx.x;
  int bh = blockIdx.x >> 7;          // 0..95  (b*12+h)
  int qg = blockIdx.x & 127;
  int qbase = qg * G;
  const float* Kbh = kB + (size_t)bh * Nn * Dn;
  const float* Vbh = vB + (size_t)bh * Nn * Dn;
  const float* Qbh = qB + (size_t)bh * Nn * Dn;

  // stage Q rows (q already scaled by 1/8)
  for (int i = t; i < G*16; i += 512) {
    int r = i >> 4, d4 = i & 15;
    Qs[r][d4] = ((const float4*)(Qbh + (size_t)(qbase + r) * Dn))[d4];
  }
  __syncthreads();

  // ---- scores: thread = (key-base, row-half); 4 keys in flight x 4 rows ----
  {
    int th = t & 255;          // key base
    int half = t >> 8;         // 0: rows 0-3, 1: rows 4-7
    int rbase = half * 4;
    const float4* Kp0 = (const float4*)(Kbh + (size_t)(th       ) * Dn);
    const float4* Kp1 = (const float4*)(Kbh + (size_t)(th +  256) * Dn);
    const float4* Kp2 = (const float4*)(Kbh + (size_t)(th +  512) * Dn);
    const float4* Kp3 = (const float4*)(Kbh + (size_t)(th +  768) * Dn);
    float acc[4][4] = {};      // [row'][c]
#pragma unroll
    for (int d4 = 0; d4 < 16; ++d4) {
      float4 kx0 = Kp0[d4], kx1 = Kp1[d4], kx2 = Kp2[d4], kx3 = Kp3[d4];
#pragma unroll
      for (int rr = 0; rr < 4; ++rr) {
        float4 q4 = Qs[rbase + rr][d4];   // uniform LDS read -> broadcast
        // fma chain order identical to R1-R3 (bit-identical scores)
        acc[rr][0] = fmaf(q4.x,kx0.x, fmaf(q4.y,kx0.y, fmaf(q4.z,kx0.z, fmaf(q4.w,kx0.w, acc[rr][0]))));
        acc[rr][1] = fmaf(q4.x,kx1.x, fmaf(q4.y,kx1.y, fmaf(q4.z,kx1.z, fmaf(q4.w,kx1.w, acc[rr][1]))));
        acc[rr][2] = fmaf(q4.x,kx2.x, fmaf(q4.y,kx2.y, fmaf(q4.z,kx2.z, fmaf(q4.w,kx2.w, acc[rr][2]))));
        acc[rr][3] = fmaf(q4.x,kx3.x, fmaf(q4.y,kx3.y, fmaf(q4.z,kx3.z, fmaf(q4.w,kx3.w, acc[rr][3]))));
      }
    }
#pragma unroll
    for (int rr = 0; rr < 4; ++rr) {
      Ws[rbase+rr][th      ] = acc[rr][0];
      Ws[rbase+rr][th + 256] = acc[rr][1];
      Ws[rbase+rr][th + 512] = acc[rr][2];
      Ws[rbase+rr][th + 768] = acc[rr][3];
    }
  }
  __syncthreads();

  // ---- wave-private: row w, 16 scores per lane (j = lane + 64*i) ----
  int w = t >> 6, lane = t & 63;
  float f[16];
  unsigned u[16];
#pragma unroll
  for (int i = 0; i < 16; ++i) {
    f[i] = Ws[w][lane + 64*i];     // stride-64: 2-way bank alias (free)
    u[i] = toOrd(f[i]);
  }

  // row max (order-independent -> exact same value as before)
  float mloc = f[0];
#pragma unroll
  for (int i = 1; i < 16; ++i) mloc = fmaxf(mloc, f[i]);
  float m = wave_max_f32(mloc);

  // ---- exact k-th largest: bisection + DPP count + early exit -------------
  int kval = *kptr;                       // uniform
  bool doSel = (kval > 0 && kval < Nn);
  unsigned thr = 0u;                      // thr=0 keeps everything
  if (doSel) {
    unsigned res = 0u;
    for (int bit = 31; bit >= 0; --bit) {
      unsigned cand = res | (1u << bit);
      int c = 0;
#pragma unroll
      for (int i = 0; i < 16; ++i) c += (u[i] >= cand) ? 1 : 0;
      int ct = wave_sum_i32(c);
      if (ct == kval) {                   // candidate separates k-th / k+1-th:
        unsigned mn = 0xFFFFFFFFu;        // k-th largest = min survivor
#pragma unroll
        for (int i = 0; i < 16; ++i)
          if (u[i] >= cand && u[i] < mn) mn = u[i];
        res = wave_min_u32(mn);
        break;
      }
      if (ct > kval) res = cand;
    }
    thr = res;   // exact bit pattern of the k-th largest score
  }

  // ---- weights + ballot compaction into tail of own Ws row ----------------
  float2* Pair = (float2*)&Ws[w][1024 - 2*CAP];   // scores there already in regs
  float Zl = 0.f;
  int cnt = 0;
#pragma unroll
  for (int i = 0; i < 16; ++i) {
    bool keep = (u[i] >= thr);
    unsigned long long msk = __ballot(keep);
    if (keep) {
      float wgt = __expf(f[i] - m);
      Zl += wgt;                        // Z over ALL survivors
      int pos = cnt + __popcll(msk & ((1ull << lane) - 1ull));
      if (pos < CAP) {
        float2 p; p.x = wgt; p.y = __int_as_float(lane + 64*i);
        Pair[pos] = p;
      }
    }
    cnt += __popcll(msk);
  }
  float Z = wave_sum_f32(Zl);

  // ---- PV: lane = output dim; same-wave DS ops are in-order (no barrier) --
  float acc = 0.f;
  if (cnt <= CAP) {
    int i = 0;
    for (; i + 4 <= cnt; i += 4) {
      float2 p0 = Pair[i],   p1 = Pair[i+1];
      float2 p2 = Pair[i+2], p3 = Pair[i+3];
      int j0 = __float_as_int(p0.y), j1 = __float_as_int(p1.y);
      int j2 = __float_as_int(p2.y), j3 = __float_as_int(p3.y);
      float v0 = Vbh[(size_t)j0*Dn + lane];
      float v1 = Vbh[(size_t)j1*Dn + lane];
      float v2 = Vbh[(size_t)j2*Dn + lane];
      float v3 = Vbh[(size_t)j3*Dn + lane];
      acc = fmaf(p0.x, v0, acc);
      acc = fmaf(p1.x, v1, acc);
      acc = fmaf(p2.x, v2, acc);
      acc = fmaf(p3.x, v3, acc);
    }
    for (; i < cnt; ++i) {
      float2 p = Pair[i];
      acc = fmaf(p.x, Vbh[(size_t)__float_as_int(p.y)*Dn + lane], acc);
    }
  } else {
    // tie-overflow fallback (rare): rewrite full weight row from registers
    // (repairs any tail clobbered by Pair writes), then walk all keys (j asc,
    // same order as compaction would have produced).
#pragma unroll
    for (int i = 0; i < 16; ++i)
      Ws[w][lane + 64*i] = (u[i] >= thr) ? __expf(f[i] - m) : 0.f;
    for (int j = 0; j < 1024; ++j) {
      float wgt = Ws[w][j];
      if (wgt != 0.f) acc = fmaf(wgt, Vbh[(size_t)j*Dn + lane], acc);
    }
  }

  int b = bh / Hn, h = bh - b*Hn;
  out[((size_t)(b*Nn + qbase + w))*Cn + h*Dn + lane] = acc * (1.0f / Z);
}

extern "C" void kernel_launch(void* const* d_in, const int* in_sizes, int n_in,
                              void* d_out, int out_size, void* d_ws, size_t ws_size,
                              hipStream_t stream) {
  const float* x      = (const float*)d_in[0];
  const float* qkv_w  = (const float*)d_in[1];
  const float* qkv_b  = (const float*)d_in[2];
  const float* proj_w = (const float*)d_in[3];
  const float* proj_b = (const float*)d_in[4];
  const int*   kptr   = (const int*)d_in[5];

  float* ws  = (float*)d_ws;
  const size_t sz = (size_t)Bn * Hn * Nn * Dn;   // 6291456 elements
  float* qbuf = ws;
  float* kbuf = ws + sz;
  float* vbuf = ws + 2*sz;
  float* att  = ws + 3*sz;                       // (B,N,C)
  float* outp = (float*)d_out;

  qkv_gemm<<<dim3(18*64), 256, 0, stream>>>(x, qkv_w, qkv_b, qbuf, kbuf, vbuf);
  attn_kernel<<<dim3(Bn*Hn*(Nn/8)), 512, 0, stream>>>(qbuf, kbuf, vbuf, kptr, att);
  proj_gemm<<<dim3(6*64), 256, 0, stream>>>(att, proj_w, proj_b, outp);
}

// Round 5
// 1981.618 us; speedup vs baseline: 1.0782x; 1.0782x over previous
//
#include <hip/hip_runtime.h>

constexpr int Bn = 8, Nn = 1024, Cn = 768, Hn = 12, Dn = 64;

__device__ __forceinline__ unsigned toOrd(float f) {
  unsigned u = __float_as_uint(f);
  return (u & 0x80000000u) ? ~u : (u | 0x80000000u);
}
__device__ __forceinline__ float invOrd(unsigned v) {
  unsigned b = (v & 0x80000000u) ? (v & 0x7FFFFFFFu) : ~v;
  return __uint_as_float(b);
}

// ---- wave64 reductions via DPP (pure VALU: no LDS, no SALU hazards) --------
__device__ __forceinline__ int wave_sum_i32(int x) {
  x += __builtin_amdgcn_update_dpp(0, x, 0x111, 0xF, 0xF, false);
  x += __builtin_amdgcn_update_dpp(0, x, 0x112, 0xF, 0xF, false);
  x += __builtin_amdgcn_update_dpp(0, x, 0x114, 0xF, 0xF, false);
  x += __builtin_amdgcn_update_dpp(0, x, 0x118, 0xF, 0xF, false);
  x += __builtin_amdgcn_update_dpp(0, x, 0x142, 0xA, 0xF, false);
  x += __builtin_amdgcn_update_dpp(0, x, 0x143, 0xC, 0xF, false);
  return __builtin_amdgcn_readlane(x, 63);
}
__device__ __forceinline__ float wave_sum_f32(float x) {
  int xi = __float_as_int(x);
  x += __int_as_float(__builtin_amdgcn_update_dpp(0, xi, 0x111, 0xF, 0xF, false)); xi = __float_as_int(x);
  x += __int_as_float(__builtin_amdgcn_update_dpp(0, xi, 0x112, 0xF, 0xF, false)); xi = __float_as_int(x);
  x += __int_as_float(__builtin_amdgcn_update_dpp(0, xi, 0x114, 0xF, 0xF, false)); xi = __float_as_int(x);
  x += __int_as_float(__builtin_amdgcn_update_dpp(0, xi, 0x118, 0xF, 0xF, false)); xi = __float_as_int(x);
  x += __int_as_float(__builtin_amdgcn_update_dpp(0, xi, 0x142, 0xA, 0xF, false)); xi = __float_as_int(x);
  x += __int_as_float(__builtin_amdgcn_update_dpp(0, xi, 0x143, 0xC, 0xF, false));
  return __int_as_float(__builtin_amdgcn_readlane(__float_as_int(x), 63));
}
__device__ __forceinline__ unsigned wave_max_u32(unsigned x) {
  int xi = (int)x;              // old = self: identity under max
  x = max(x, (unsigned)__builtin_amdgcn_update_dpp(xi, xi, 0x111, 0xF, 0xF, false)); xi = (int)x;
  x = max(x, (unsigned)__builtin_amdgcn_update_dpp(xi, xi, 0x112, 0xF, 0xF, false)); xi = (int)x;
  x = max(x, (unsigned)__builtin_amdgcn_update_dpp(xi, xi, 0x114, 0xF, 0xF, false)); xi = (int)x;
  x = max(x, (unsigned)__builtin_amdgcn_update_dpp(xi, xi, 0x118, 0xF, 0xF, false)); xi = (int)x;
  x = max(x, (unsigned)__builtin_amdgcn_update_dpp(xi, xi, 0x142, 0xA, 0xF, false)); xi = (int)x;
  x = max(x, (unsigned)__builtin_amdgcn_update_dpp(xi, xi, 0x143, 0xC, 0xF, false));
  return (unsigned)__builtin_amdgcn_readlane((int)x, 63);
}
__device__ __forceinline__ unsigned wave_min_u32(unsigned x) {
  int xi = (int)x;              // old = self: identity under min
  x = min(x, (unsigned)__builtin_amdgcn_update_dpp(xi, xi, 0x111, 0xF, 0xF, false)); xi = (int)x;
  x = min(x, (unsigned)__builtin_amdgcn_update_dpp(xi, xi, 0x112, 0xF, 0xF, false)); xi = (int)x;
  x = min(x, (unsigned)__builtin_amdgcn_update_dpp(xi, xi, 0x114, 0xF, 0xF, false)); xi = (int)x;
  x = min(x, (unsigned)__builtin_amdgcn_update_dpp(xi, xi, 0x118, 0xF, 0xF, false)); xi = (int)x;
  x = min(x, (unsigned)__builtin_amdgcn_update_dpp(xi, xi, 0x142, 0xA, 0xF, false)); xi = (int)x;
  x = min(x, (unsigned)__builtin_amdgcn_update_dpp(xi, xi, 0x143, 0xC, 0xF, false));
  return (unsigned)__builtin_amdgcn_readlane((int)x, 63);
}

// ---------------- QKV GEMM (128x128 tile, 8x8 acc): qkv = x@W^T + b ---------
__global__ __launch_bounds__(256, 4) void qkv_gemm(
    const float* __restrict__ X, const float* __restrict__ Wm,
    const float* __restrict__ bias,
    float* __restrict__ qb, float* __restrict__ kb, float* __restrict__ vb)
{
  constexpr int BK = 16, LD = 132;
  __shared__ float As[BK][LD];
  __shared__ float Bs[BK][LD];
  int t = threadIdx.x;
  int mt = blockIdx.x & 63;         // 64 m-tiles
  int nt = blockIdx.x >> 6;         // 18 n-tiles
  int m0 = mt * 128, n0 = nt * 128;
  int sr = t >> 1;                  // staging row 0..127
  int sk = (t & 1) * 8;             // staging k 0 or 8
  const float* Ap = X  + (size_t)(m0 + sr) * Cn + sk;
  const float* Bp = Wm + (size_t)(n0 + sr) * Cn + sk;
  int tm = t >> 4, tn = t & 15;
  float acc[8][8] = {};
  for (int k0 = 0; k0 < Cn; k0 += BK) {
    float4 a0 = *(const float4*)(Ap + k0);
    float4 a1 = *(const float4*)(Ap + k0 + 4);
    float4 b0 = *(const float4*)(Bp + k0);
    float4 b1 = *(const float4*)(Bp + k0 + 4);
    __syncthreads();
    As[sk+0][sr]=a0.x; As[sk+1][sr]=a0.y; As[sk+2][sr]=a0.z; As[sk+3][sr]=a0.w;
    As[sk+4][sr]=a1.x; As[sk+5][sr]=a1.y; As[sk+6][sr]=a1.z; As[sk+7][sr]=a1.w;
    Bs[sk+0][sr]=b0.x; Bs[sk+1][sr]=b0.y; Bs[sk+2][sr]=b0.z; Bs[sk+3][sr]=b0.w;
    Bs[sk+4][sr]=b1.x; Bs[sk+5][sr]=b1.y; Bs[sk+6][sr]=b1.z; Bs[sk+7][sr]=b1.w;
    __syncthreads();
#pragma unroll
    for (int kk = 0; kk < BK; ++kk) {
      float4 x0 = *(const float4*)(&As[kk][tm*8]);
      float4 x1 = *(const float4*)(&As[kk][tm*8+4]);
      float4 y0 = *(const float4*)(&Bs[kk][tn*8]);
      float4 y1 = *(const float4*)(&Bs[kk][tn*8+4]);
      float av[8] = {x0.x,x0.y,x0.z,x0.w,x1.x,x1.y,x1.z,x1.w};
      float bv[8] = {y0.x,y0.y,y0.z,y0.w,y1.x,y1.y,y1.z,y1.w};
#pragma unroll
      for (int i = 0; i < 8; ++i)
#pragma unroll
        for (int j = 0; j < 8; ++j) acc[i][j] = fmaf(av[i], bv[j], acc[i][j]);
    }
  }
  int c0 = n0 + tn*8;
  int which = c0 / Cn;
  int rem0 = c0 - which*Cn;
  float* dst = which == 0 ? qb : (which == 1 ? kb : vb);
  float sc = which == 0 ? 0.125f : 1.0f;   // q pre-scaled by d^-0.5
  float4 bs0 = *(const float4*)(bias + c0);
  float4 bs1 = *(const float4*)(bias + c0 + 4);
  int h0 = rem0 >> 6, dd0 = rem0 & 63;
#pragma unroll
  for (int i = 0; i < 8; ++i) {
    int mrow = m0 + tm*8 + i;
    int bbi = mrow >> 10, n = mrow & 1023;
    size_t base = (((size_t)(bbi*Hn + h0))*Nn + n)*Dn + dd0;
    float4 o0, o1;
    o0.x=(acc[i][0]+bs0.x)*sc; o0.y=(acc[i][1]+bs0.y)*sc; o0.z=(acc[i][2]+bs0.z)*sc; o0.w=(acc[i][3]+bs0.w)*sc;
    o1.x=(acc[i][4]+bs1.x)*sc; o1.y=(acc[i][5]+bs1.y)*sc; o1.z=(acc[i][6]+bs1.z)*sc; o1.w=(acc[i][7]+bs1.w)*sc;
    *(float4*)(dst + base)     = o0;
    *(float4*)(dst + base + 4) = o1;
  }
}

// ---------------- Proj GEMM (128x128 tile, 8x8 acc): out = att@W^T + b ------
__global__ __launch_bounds__(256, 4) void proj_gemm(
    const float* __restrict__ X, const float* __restrict__ Wm,
    const float* __restrict__ bias, float* __restrict__ Out)
{
  constexpr int BK = 16, LD = 132;
  __shared__ float As[BK][LD];
  __shared__ float Bs[BK][LD];
  int t = threadIdx.x;
  int mt = blockIdx.x & 63;
  int nt = blockIdx.x >> 6;         // 6 n-tiles
  int m0 = mt * 128, n0 = nt * 128;
  int sr = t >> 1;
  int sk = (t & 1) * 8;
  const float* Ap = X  + (size_t)(m0 + sr) * Cn + sk;
  const float* Bp = Wm + (size_t)(n0 + sr) * Cn + sk;
  int tm = t >> 4, tn = t & 15;
  float acc[8][8] = {};
  for (int k0 = 0; k0 < Cn; k0 += BK) {
    float4 a0 = *(const float4*)(Ap + k0);
    float4 a1 = *(const float4*)(Ap + k0 + 4);
    float4 b0 = *(const float4*)(Bp + k0);
    float4 b1 = *(const float4*)(Bp + k0 + 4);
    __syncthreads();
    As[sk+0][sr]=a0.x; As[sk+1][sr]=a0.y; As[sk+2][sr]=a0.z; As[sk+3][sr]=a0.w;
    As[sk+4][sr]=a1.x; As[sk+5][sr]=a1.y; As[sk+6][sr]=a1.z; As[sk+7][sr]=a1.w;
    Bs[sk+0][sr]=b0.x; Bs[sk+1][sr]=b0.y; Bs[sk+2][sr]=b0.z; Bs[sk+3][sr]=b0.w;
    Bs[sk+4][sr]=b1.x; Bs[sk+5][sr]=b1.y; Bs[sk+6][sr]=b1.z; Bs[sk+7][sr]=b1.w;
    __syncthreads();
#pragma unroll
    for (int kk = 0; kk < BK; ++kk) {
      float4 x0 = *(const float4*)(&As[kk][tm*8]);
      float4 x1 = *(const float4*)(&As[kk][tm*8+4]);
      float4 y0 = *(const float4*)(&Bs[kk][tn*8]);
      float4 y1 = *(const float4*)(&Bs[kk][tn*8+4]);
      float av[8] = {x0.x,x0.y,x0.z,x0.w,x1.x,x1.y,x1.z,x1.w};
      float bv[8] = {y0.x,y0.y,y0.z,y0.w,y1.x,y1.y,y1.z,y1.w};
#pragma unroll
      for (int i = 0; i < 8; ++i)
#pragma unroll
        for (int j = 0; j < 8; ++j) acc[i][j] = fmaf(av[i], bv[j], acc[i][j]);
    }
  }
  int c0 = n0 + tn*8;
  float4 bs0 = *(const float4*)(bias + c0);
  float4 bs1 = *(const float4*)(bias + c0 + 4);
#pragma unroll
  for (int i = 0; i < 8; ++i) {
    int mrow = m0 + tm*8 + i;
    float4 o0, o1;
    o0.x=acc[i][0]+bs0.x; o0.y=acc[i][1]+bs0.y; o0.z=acc[i][2]+bs0.z; o0.w=acc[i][3]+bs0.w;
    o1.x=acc[i][4]+bs1.x; o1.y=acc[i][5]+bs1.y; o1.z=acc[i][6]+bs1.z; o1.w=acc[i][7]+bs1.w;
    *(float4*)(Out + (size_t)mrow*Cn + c0)     = o0;
    *(float4*)(Out + (size_t)mrow*Cn + c0 + 4) = o1;
  }
}

// ---------------- Attention: scores + DPP-bisect exact top-k + softmax + PV -
// One block = (b,h) x 8 q-rows, 512 threads = 8 waves; wave w owns row w.
// LDS = 34 KB. Per-lane state: ordinals only (u[16]); floats recovered exactly
// via invOrd -> ~16 fewer VGPRs than keeping f[16] too (R4's cap spilled).
__global__ __launch_bounds__(512, 4) void attn_kernel(
    const float* __restrict__ qB, const float* __restrict__ kB,
    const float* __restrict__ vB, const int* __restrict__ kptr,
    float* __restrict__ out)
{
  constexpr int G = 8, CAP = 128;
  __shared__ float  Ws[G][1024];     // scores; tail of own row reused for pairs
  __shared__ float4 Qs[G][16];       // 2 KB

  int t = threadIdx.x;
  int bh = blockIdx.x >> 7;          // 0..95  (b*12+h)
  int qg = blockIdx.x & 127;
  int qbase = qg * G;
  const float* Kbh = kB + (size_t)bh * Nn * Dn;
  const float* Vbh = vB + (size_t)bh * Nn * Dn;
  const float* Qbh = qB + (size_t)bh * Nn * Dn;

  // stage Q rows (q already scaled by 1/8)
  for (int i = t; i < G*16; i += 512) {
    int r = i >> 4, d4 = i & 15;
    Qs[r][d4] = ((const float4*)(Qbh + (size_t)(qbase + r) * Dn))[d4];
  }
  __syncthreads();

  // ---- scores: thread = (key-base, row-half); 4 keys in flight x 4 rows ----
  {
    int th = t & 255;          // key base
    int half = t >> 8;         // 0: rows 0-3, 1: rows 4-7
    int rbase = half * 4;
    const float4* Kp0 = (const float4*)(Kbh + (size_t)(th       ) * Dn);
    const float4* Kp1 = (const float4*)(Kbh + (size_t)(th +  256) * Dn);
    const float4* Kp2 = (const float4*)(Kbh + (size_t)(th +  512) * Dn);
    const float4* Kp3 = (const float4*)(Kbh + (size_t)(th +  768) * Dn);
    float acc[4][4] = {};      // [row'][c]
#pragma unroll
    for (int d4 = 0; d4 < 16; ++d4) {
      float4 kx0 = Kp0[d4], kx1 = Kp1[d4], kx2 = Kp2[d4], kx3 = Kp3[d4];
#pragma unroll
      for (int rr = 0; rr < 4; ++rr) {
        float4 q4 = Qs[rbase + rr][d4];   // uniform LDS read -> broadcast
        // fma chain order identical to R1-R4 (bit-identical scores)
        acc[rr][0] = fmaf(q4.x,kx0.x, fmaf(q4.y,kx0.y, fmaf(q4.z,kx0.z, fmaf(q4.w,kx0.w, acc[rr][0]))));
        acc[rr][1] = fmaf(q4.x,kx1.x, fmaf(q4.y,kx1.y, fmaf(q4.z,kx1.z, fmaf(q4.w,kx1.w, acc[rr][1]))));
        acc[rr][2] = fmaf(q4.x,kx2.x, fmaf(q4.y,kx2.y, fmaf(q4.z,kx2.z, fmaf(q4.w,kx2.w, acc[rr][2]))));
        acc[rr][3] = fmaf(q4.x,kx3.x, fmaf(q4.y,kx3.y, fmaf(q4.z,kx3.z, fmaf(q4.w,kx3.w, acc[rr][3]))));
      }
    }
#pragma unroll
    for (int rr = 0; rr < 4; ++rr) {
      Ws[rbase+rr][th      ] = acc[rr][0];
      Ws[rbase+rr][th + 256] = acc[rr][1];
      Ws[rbase+rr][th + 512] = acc[rr][2];
      Ws[rbase+rr][th + 768] = acc[rr][3];
    }
  }
  __syncthreads();

  // ---- wave-private: row w, 16 ordinals per lane (j = lane + 64*i) ----
  int w = t >> 6, lane = t & 63;
  unsigned u[16];
#pragma unroll
  for (int i = 0; i < 16; ++i)
    u[i] = toOrd(Ws[w][lane + 64*i]);   // stride-64: 2-way bank alias (free)

  // row max in ordinal domain (order-isomorphic -> same value exactly)
  unsigned mu = u[0];
#pragma unroll
  for (int i = 1; i < 16; ++i) mu = max(mu, u[i]);
  float m = invOrd(wave_max_u32(mu));

  // ---- exact k-th largest: bisection + DPP count + early exit -------------
  int kval = *kptr;                       // uniform
  bool doSel = (kval > 0 && kval < Nn);
  unsigned thr = 0u;                      // thr=0 keeps everything
  if (doSel) {
    unsigned res = 0u;
    for (int bit = 31; bit >= 0; --bit) {
      unsigned cand = res | (1u << bit);
      int c = 0;
#pragma unroll
      for (int i = 0; i < 16; ++i) c += (u[i] >= cand) ? 1 : 0;
      int ct = wave_sum_i32(c);
      if (ct == kval) {                   // candidate separates k-th / k+1-th:
        unsigned mn = 0xFFFFFFFFu;        // k-th largest = min survivor
#pragma unroll
        for (int i = 0; i < 16; ++i)
          if (u[i] >= cand && u[i] < mn) mn = u[i];
        res = wave_min_u32(mn);
        break;
      }
      if (ct > kval) res = cand;
    }
    thr = res;   // exact bit pattern of the k-th largest score
  }

  // ---- weights + ballot compaction into tail of own Ws row ----------------
  float2* Pair = (float2*)&Ws[w][1024 - 2*CAP];
  float Zl = 0.f;
  int cnt = 0;
#pragma unroll
  for (int i = 0; i < 16; ++i) {
    bool keep = (u[i] >= thr);
    unsigned long long msk = __ballot(keep);
    if (keep) {
      float wgt = __expf(invOrd(u[i]) - m);
      Zl += wgt;                        // Z over ALL survivors
      int pos = cnt + __popcll(msk & ((1ull << lane) - 1ull));
      if (pos < CAP) {
        float2 p; p.x = wgt; p.y = __int_as_float(lane + 64*i);
        Pair[pos] = p;
      }
    }
    cnt += __popcll(msk);
  }
  float Z = wave_sum_f32(Zl);

  // ---- PV: lane = output dim; same-wave DS ops are in-order (no barrier) --
  float acc = 0.f;
  if (cnt <= CAP) {
    int i = 0;
    for (; i + 4 <= cnt; i += 4) {
      float2 p0 = Pair[i],   p1 = Pair[i+1];
      float2 p2 = Pair[i+2], p3 = Pair[i+3];
      int j0 = __float_as_int(p0.y), j1 = __float_as_int(p1.y);
      int j2 = __float_as_int(p2.y), j3 = __float_as_int(p3.y);
      float v0 = Vbh[(size_t)j0*Dn + lane];
      float v1 = Vbh[(size_t)j1*Dn + lane];
      float v2 = Vbh[(size_t)j2*Dn + lane];
      float v3 = Vbh[(size_t)j3*Dn + lane];
      acc = fmaf(p0.x, v0, acc);
      acc = fmaf(p1.x, v1, acc);
      acc = fmaf(p2.x, v2, acc);
      acc = fmaf(p3.x, v3, acc);
    }
    for (; i < cnt; ++i) {
      float2 p = Pair[i];
      acc = fmaf(p.x, Vbh[(size_t)__float_as_int(p.y)*Dn + lane], acc);
    }
  } else {
    // tie-overflow fallback (rare): rewrite full weight row from ordinals
    // (repairs any tail clobbered by Pair writes), then walk all keys.
#pragma unroll
    for (int i = 0; i < 16; ++i)
      Ws[w][lane + 64*i] = (u[i] >= thr) ? __expf(invOrd(u[i]) - m) : 0.f;
    for (int j = 0; j < 1024; ++j) {
      float wgt = Ws[w][j];
      if (wgt != 0.f) acc = fmaf(wgt, Vbh[(size_t)j*Dn + lane], acc);
    }
  }

  int b = bh / Hn, h = bh - b*Hn;
  out[((size_t)(b*Nn + qbase + w))*Cn + h*Dn + lane] = acc * (1.0f / Z);
}

extern "C" void kernel_launch(void* const* d_in, const int* in_sizes, int n_in,
                              void* d_out, int out_size, void* d_ws, size_t ws_size,
                              hipStream_t stream) {
  const float* x      = (const float*)d_in[0];
  const float* qkv_w  = (const float*)d_in[1];
  const float* qkv_b  = (const float*)d_in[2];
  const float* proj_w = (const float*)d_in[3];
  const float* proj_b = (const float*)d_in[4];
  const int*   kptr   = (const int*)d_in[5];

  float* ws  = (float*)d_ws;
  const size_t sz = (size_t)Bn * Hn * Nn * Dn;   // 6291456 elements
  float* qbuf = ws;
  float* kbuf = ws + sz;
  float* vbuf = ws + 2*sz;
  float* att  = ws + 3*sz;                       // (B,N,C)
  float* outp = (float*)d_out;

  qkv_gemm<<<dim3(18*64), 256, 0, stream>>>(x, qkv_w, qkv_b, qbuf, kbuf, vbuf);
  attn_kernel<<<dim3(Bn*Hn*(Nn/8)), 512, 0, stream>>>(qbuf, kbuf, vbuf, kptr, att);
  proj_gemm<<<dim3(6*64), 256, 0, stream>>>(att, proj_w, proj_b, outp);
}

// Round 6
// 1066.198 us; speedup vs baseline: 2.0039x; 1.8586x over previous
//
#include <hip/hip_runtime.h>

constexpr int Bn = 8, Nn = 1024, Cn = 768, Hn = 12, Dn = 64;

__device__ __forceinline__ unsigned toOrd(float f) {
  unsigned u = __float_as_uint(f);
  return (u & 0x80000000u) ? ~u : (u | 0x80000000u);
}
__device__ __forceinline__ float invOrd(unsigned v) {
  unsigned b = (v & 0x80000000u) ? (v & 0x7FFFFFFFu) : ~v;
  return __uint_as_float(b);
}

// ---- wave64 reductions via DPP (pure VALU: no LDS, no SALU hazards) --------
__device__ __forceinline__ int wave_sum_i32(int x) {
  x += __builtin_amdgcn_update_dpp(0, x, 0x111, 0xF, 0xF, false);
  x += __builtin_amdgcn_update_dpp(0, x, 0x112, 0xF, 0xF, false);
  x += __builtin_amdgcn_update_dpp(0, x, 0x114, 0xF, 0xF, false);
  x += __builtin_amdgcn_update_dpp(0, x, 0x118, 0xF, 0xF, false);
  x += __builtin_amdgcn_update_dpp(0, x, 0x142, 0xA, 0xF, false);
  x += __builtin_amdgcn_update_dpp(0, x, 0x143, 0xC, 0xF, false);
  return __builtin_amdgcn_readlane(x, 63);
}
__device__ __forceinline__ float wave_sum_f32(float x) {
  int xi = __float_as_int(x);
  x += __int_as_float(__builtin_amdgcn_update_dpp(0, xi, 0x111, 0xF, 0xF, false)); xi = __float_as_int(x);
  x += __int_as_float(__builtin_amdgcn_update_dpp(0, xi, 0x112, 0xF, 0xF, false)); xi = __float_as_int(x);
  x += __int_as_float(__builtin_amdgcn_update_dpp(0, xi, 0x114, 0xF, 0xF, false)); xi = __float_as_int(x);
  x += __int_as_float(__builtin_amdgcn_update_dpp(0, xi, 0x118, 0xF, 0xF, false)); xi = __float_as_int(x);
  x += __int_as_float(__builtin_amdgcn_update_dpp(0, xi, 0x142, 0xA, 0xF, false)); xi = __float_as_int(x);
  x += __int_as_float(__builtin_amdgcn_update_dpp(0, xi, 0x143, 0xC, 0xF, false));
  return __int_as_float(__builtin_amdgcn_readlane(__float_as_int(x), 63));
}
__device__ __forceinline__ unsigned wave_max_u32(unsigned x) {
  int xi = (int)x;              // old = self: identity under max
  x = max(x, (unsigned)__builtin_amdgcn_update_dpp(xi, xi, 0x111, 0xF, 0xF, false)); xi = (int)x;
  x = max(x, (unsigned)__builtin_amdgcn_update_dpp(xi, xi, 0x112, 0xF, 0xF, false)); xi = (int)x;
  x = max(x, (unsigned)__builtin_amdgcn_update_dpp(xi, xi, 0x114, 0xF, 0xF, false)); xi = (int)x;
  x = max(x, (unsigned)__builtin_amdgcn_update_dpp(xi, xi, 0x118, 0xF, 0xF, false)); xi = (int)x;
  x = max(x, (unsigned)__builtin_amdgcn_update_dpp(xi, xi, 0x142, 0xA, 0xF, false)); xi = (int)x;
  x = max(x, (unsigned)__builtin_amdgcn_update_dpp(xi, xi, 0x143, 0xC, 0xF, false));
  return (unsigned)__builtin_amdgcn_readlane((int)x, 63);
}
__device__ __forceinline__ unsigned wave_min_u32(unsigned x) {
  int xi = (int)x;              // old = self: identity under min
  x = min(x, (unsigned)__builtin_amdgcn_update_dpp(xi, xi, 0x111, 0xF, 0xF, false)); xi = (int)x;
  x = min(x, (unsigned)__builtin_amdgcn_update_dpp(xi, xi, 0x112, 0xF, 0xF, false)); xi = (int)x;
  x = min(x, (unsigned)__builtin_amdgcn_update_dpp(xi, xi, 0x114, 0xF, 0xF, false)); xi = (int)x;
  x = min(x, (unsigned)__builtin_amdgcn_update_dpp(xi, xi, 0x118, 0xF, 0xF, false)); xi = (int)x;
  x = min(x, (unsigned)__builtin_amdgcn_update_dpp(xi, xi, 0x142, 0xA, 0xF, false)); xi = (int)x;
  x = min(x, (unsigned)__builtin_amdgcn_update_dpp(xi, xi, 0x143, 0xC, 0xF, false));
  return (unsigned)__builtin_amdgcn_readlane((int)x, 63);
}

// ---------------- QKV GEMM (128x128 tile, 8x8 acc): qkv = x@W^T + b ---------
__global__ __launch_bounds__(256, 4) void qkv_gemm(
    const float* __restrict__ X, const float* __restrict__ Wm,
    const float* __restrict__ bias,
    float* __restrict__ qb, float* __restrict__ kb, float* __restrict__ vb)
{
  constexpr int BK = 16, LD = 132;
  __shared__ float As[BK][LD];
  __shared__ float Bs[BK][LD];
  int t = threadIdx.x;
  int mt = blockIdx.x & 63;         // 64 m-tiles
  int nt = blockIdx.x >> 6;         // 18 n-tiles
  int m0 = mt * 128, n0 = nt * 128;
  int sr = t >> 1;                  // staging row 0..127
  int sk = (t & 1) * 8;             // staging k 0 or 8
  const float* Ap = X  + (size_t)(m0 + sr) * Cn + sk;
  const float* Bp = Wm + (size_t)(n0 + sr) * Cn + sk;
  int tm = t >> 4, tn = t & 15;
  float acc[8][8] = {};
  for (int k0 = 0; k0 < Cn; k0 += BK) {
    float4 a0 = *(const float4*)(Ap + k0);
    float4 a1 = *(const float4*)(Ap + k0 + 4);
    float4 b0 = *(const float4*)(Bp + k0);
    float4 b1 = *(const float4*)(Bp + k0 + 4);
    __syncthreads();
    As[sk+0][sr]=a0.x; As[sk+1][sr]=a0.y; As[sk+2][sr]=a0.z; As[sk+3][sr]=a0.w;
    As[sk+4][sr]=a1.x; As[sk+5][sr]=a1.y; As[sk+6][sr]=a1.z; As[sk+7][sr]=a1.w;
    Bs[sk+0][sr]=b0.x; Bs[sk+1][sr]=b0.y; Bs[sk+2][sr]=b0.z; Bs[sk+3][sr]=b0.w;
    Bs[sk+4][sr]=b1.x; Bs[sk+5][sr]=b1.y; Bs[sk+6][sr]=b1.z; Bs[sk+7][sr]=b1.w;
    __syncthreads();
#pragma unroll
    for (int kk = 0; kk < BK; ++kk) {
      float4 x0 = *(const float4*)(&As[kk][tm*8]);
      float4 x1 = *(const float4*)(&As[kk][tm*8+4]);
      float4 y0 = *(const float4*)(&Bs[kk][tn*8]);
      float4 y1 = *(const float4*)(&Bs[kk][tn*8+4]);
      float av[8] = {x0.x,x0.y,x0.z,x0.w,x1.x,x1.y,x1.z,x1.w};
      float bv[8] = {y0.x,y0.y,y0.z,y0.w,y1.x,y1.y,y1.z,y1.w};
#pragma unroll
      for (int i = 0; i < 8; ++i)
#pragma unroll
        for (int j = 0; j < 8; ++j) acc[i][j] = fmaf(av[i], bv[j], acc[i][j]);
    }
  }
  int c0 = n0 + tn*8;
  int which = c0 / Cn;
  int rem0 = c0 - which*Cn;
  float* dst = which == 0 ? qb : (which == 1 ? kb : vb);
  float sc = which == 0 ? 0.125f : 1.0f;   // q pre-scaled by d^-0.5
  float4 bs0 = *(const float4*)(bias + c0);
  float4 bs1 = *(const float4*)(bias + c0 + 4);
  int h0 = rem0 >> 6, dd0 = rem0 & 63;
#pragma unroll
  for (int i = 0; i < 8; ++i) {
    int mrow = m0 + tm*8 + i;
    int bbi = mrow >> 10, n = mrow & 1023;
    size_t base = (((size_t)(bbi*Hn + h0))*Nn + n)*Dn + dd0;
    float4 o0, o1;
    o0.x=(acc[i][0]+bs0.x)*sc; o0.y=(acc[i][1]+bs0.y)*sc; o0.z=(acc[i][2]+bs0.z)*sc; o0.w=(acc[i][3]+bs0.w)*sc;
    o1.x=(acc[i][4]+bs1.x)*sc; o1.y=(acc[i][5]+bs1.y)*sc; o1.z=(acc[i][6]+bs1.z)*sc; o1.w=(acc[i][7]+bs1.w)*sc;
    *(float4*)(dst + base)     = o0;
    *(float4*)(dst + base + 4) = o1;
  }
}

// ---------------- Proj GEMM (128x128 tile, 8x8 acc): out = att@W^T + b ------
__global__ __launch_bounds__(256, 4) void proj_gemm(
    const float* __restrict__ X, const float* __restrict__ Wm,
    const float* __restrict__ bias, float* __restrict__ Out)
{
  constexpr int BK = 16, LD = 132;
  __shared__ float As[BK][LD];
  __shared__ float Bs[BK][LD];
  int t = threadIdx.x;
  int mt = blockIdx.x & 63;
  int nt = blockIdx.x >> 6;         // 6 n-tiles
  int m0 = mt * 128, n0 = nt * 128;
  int sr = t >> 1;
  int sk = (t & 1) * 8;
  const float* Ap = X  + (size_t)(m0 + sr) * Cn + sk;
  const float* Bp = Wm + (size_t)(n0 + sr) * Cn + sk;
  int tm = t >> 4, tn = t & 15;
  float acc[8][8] = {};
  for (int k0 = 0; k0 < Cn; k0 += BK) {
    float4 a0 = *(const float4*)(Ap + k0);
    float4 a1 = *(const float4*)(Ap + k0 + 4);
    float4 b0 = *(const float4*)(Bp + k0);
    float4 b1 = *(const float4*)(Bp + k0 + 4);
    __syncthreads();
    As[sk+0][sr]=a0.x; As[sk+1][sr]=a0.y; As[sk+2][sr]=a0.z; As[sk+3][sr]=a0.w;
    As[sk+4][sr]=a1.x; As[sk+5][sr]=a1.y; As[sk+6][sr]=a1.z; As[sk+7][sr]=a1.w;
    Bs[sk+0][sr]=b0.x; Bs[sk+1][sr]=b0.y; Bs[sk+2][sr]=b0.z; Bs[sk+3][sr]=b0.w;
    Bs[sk+4][sr]=b1.x; Bs[sk+5][sr]=b1.y; Bs[sk+6][sr]=b1.z; Bs[sk+7][sr]=b1.w;
    __syncthreads();
#pragma unroll
    for (int kk = 0; kk < BK; ++kk) {
      float4 x0 = *(const float4*)(&As[kk][tm*8]);
      float4 x1 = *(const float4*)(&As[kk][tm*8+4]);
      float4 y0 = *(const float4*)(&Bs[kk][tn*8]);
      float4 y1 = *(const float4*)(&Bs[kk][tn*8+4]);
      float av[8] = {x0.x,x0.y,x0.z,x0.w,x1.x,x1.y,x1.z,x1.w};
      float bv[8] = {y0.x,y0.y,y0.z,y0.w,y1.x,y1.y,y1.z,y1.w};
#pragma unroll
      for (int i = 0; i < 8; ++i)
#pragma unroll
        for (int j = 0; j < 8; ++j) acc[i][j] = fmaf(av[i], bv[j], acc[i][j]);
    }
  }
  int c0 = n0 + tn*8;
  float4 bs0 = *(const float4*)(bias + c0);
  float4 bs1 = *(const float4*)(bias + c0 + 4);
#pragma unroll
  for (int i = 0; i < 8; ++i) {
    int mrow = m0 + tm*8 + i;
    float4 o0, o1;
    o0.x=acc[i][0]+bs0.x; o0.y=acc[i][1]+bs0.y; o0.z=acc[i][2]+bs0.z; o0.w=acc[i][3]+bs0.w;
    o1.x=acc[i][4]+bs1.x; o1.y=acc[i][5]+bs1.y; o1.z=acc[i][6]+bs1.z; o1.w=acc[i][7]+bs1.w;
    *(float4*)(Out + (size_t)mrow*Cn + c0)     = o0;
    *(float4*)(Out + (size_t)mrow*Cn + c0 + 4) = o1;
  }
}

// ---------------- Attention: 16 q-rows/block; wave owns 2 rows sequentially -
// 512 threads = 8 waves. Score phase: thread owns keys {t, t+512} FMA'd
// against all 16 rows -> 0.25 B of L2 K-traffic per FMA (half of R2's form,
// which sat at the L2 supply limit; R3/R5's form was 2.2x over it).
// LDS = 68 KB -> 2 blocks/CU (16 waves). (512,4): VGPR cap 128, no spill.
__global__ __launch_bounds__(512, 4) void attn_kernel(
    const float* __restrict__ qB, const float* __restrict__ kB,
    const float* __restrict__ vB, const int* __restrict__ kptr,
    float* __restrict__ out)
{
  constexpr int G = 16, CAP = 128;
  __shared__ float  Ws[G][1024];     // 64 KB; tail of each row reused for pairs
  __shared__ float4 Qs[G][16];       // 4 KB

  int t = threadIdx.x;
  int bh = blockIdx.x >> 6;          // 0..95  (b*12+h)
  int qg = blockIdx.x & 63;
  int qbase = qg * G;
  const float* Kbh = kB + (size_t)bh * Nn * Dn;
  const float* Vbh = vB + (size_t)bh * Nn * Dn;
  const float* Qbh = qB + (size_t)bh * Nn * Dn;

  // stage Q rows (q already scaled by 1/8)
  for (int i = t; i < G*16; i += 512) {
    int r = i >> 4, d4 = i & 15;
    Qs[r][d4] = ((const float4*)(Qbh + (size_t)(qbase + r) * Dn))[d4];
  }
  __syncthreads();

  // ---- scores: thread owns keys {t, t+512}, all 16 rows ----
  {
    const float4* K0 = (const float4*)(Kbh + (size_t)t * Dn);
    const float4* K1 = (const float4*)(Kbh + (size_t)(t + 512) * Dn);
    float acc0[G], acc1[G];
#pragma unroll
    for (int r = 0; r < G; ++r) { acc0[r] = 0.f; acc1[r] = 0.f; }
#pragma unroll
    for (int d4 = 0; d4 < 16; ++d4) {
      float4 k0 = K0[d4], k1 = K1[d4];
#pragma unroll
      for (int r = 0; r < G; ++r) {
        float4 q4 = Qs[r][d4];   // block-uniform LDS read -> broadcast
        // fma chain order identical to R1-R5 (bit-identical scores)
        acc0[r] = fmaf(q4.x,k0.x, fmaf(q4.y,k0.y, fmaf(q4.z,k0.z, fmaf(q4.w,k0.w, acc0[r]))));
        acc1[r] = fmaf(q4.x,k1.x, fmaf(q4.y,k1.y, fmaf(q4.z,k1.z, fmaf(q4.w,k1.w, acc1[r]))));
      }
    }
#pragma unroll
    for (int r = 0; r < G; ++r) { Ws[r][t] = acc0[r]; Ws[r][t + 512] = acc1[r]; }
  }
  __syncthreads();

  // ---- selection/softmax/PV: wave owns rows 2w and 2w+1, sequentially ----
  int w = t >> 6, lane = t & 63;
  int kval = *kptr;                       // uniform
  bool doSel = (kval > 0 && kval < Nn);

  for (int p = 0; p < 2; ++p) {
    int r = w * 2 + p;
    unsigned u[16];
#pragma unroll
    for (int i = 0; i < 16; ++i)
      u[i] = toOrd(Ws[r][lane + 64*i]);   // stride-64: 2-way bank alias (free)

    // row max in ordinal domain (order-isomorphic -> same value exactly)
    unsigned mu = u[0];
#pragma unroll
    for (int i = 1; i < 16; ++i) mu = max(mu, u[i]);
    float m = invOrd(wave_max_u32(mu));

    // exact k-th largest: bisection + DPP count + early exit
    unsigned thr = 0u;                    // thr=0 keeps everything
    if (doSel) {
      unsigned res = 0u;
      for (int bit = 31; bit >= 0; --bit) {
        unsigned cand = res | (1u << bit);
        int c = 0;
#pragma unroll
        for (int i = 0; i < 16; ++i) c += (u[i] >= cand) ? 1 : 0;
        int ct = wave_sum_i32(c);
        if (ct == kval) {                 // candidate separates k-th / k+1-th:
          unsigned mn = 0xFFFFFFFFu;      // k-th largest = min survivor
#pragma unroll
          for (int i = 0; i < 16; ++i)
            if (u[i] >= cand && u[i] < mn) mn = u[i];
          res = wave_min_u32(mn);
          break;
        }
        if (ct > kval) res = cand;
      }
      thr = res;   // exact bit pattern of the k-th largest score
    }

    // weights + ballot compaction into tail of own Ws row (scores already read)
    float2* Pair = (float2*)&Ws[r][1024 - 2*CAP];
    float Zl = 0.f;
    int cnt = 0;
#pragma unroll
    for (int i = 0; i < 16; ++i) {
      bool keep = (u[i] >= thr);
      unsigned long long msk = __ballot(keep);
      if (keep) {
        float wgt = __expf(invOrd(u[i]) - m);
        Zl += wgt;                        // Z over ALL survivors
        int pos = cnt + __popcll(msk & ((1ull << lane) - 1ull));
        if (pos < CAP) {
          float2 pr; pr.x = wgt; pr.y = __int_as_float(lane + 64*i);
          Pair[pos] = pr;
        }
      }
      cnt += __popcll(msk);
    }
    float Z = wave_sum_f32(Zl);

    // PV: lane = output dim; same-wave DS ops are in-order (no barrier)
    float acc = 0.f;
    if (cnt <= CAP) {
      int i = 0;
      for (; i + 4 <= cnt; i += 4) {
        float2 p0 = Pair[i],   p1 = Pair[i+1];
        float2 p2 = Pair[i+2], p3 = Pair[i+3];
        int j0 = __float_as_int(p0.y), j1 = __float_as_int(p1.y);
        int j2 = __float_as_int(p2.y), j3 = __float_as_int(p3.y);
        float v0 = Vbh[(size_t)j0*Dn + lane];
        float v1 = Vbh[(size_t)j1*Dn + lane];
        float v2 = Vbh[(size_t)j2*Dn + lane];
        float v3 = Vbh[(size_t)j3*Dn + lane];
        acc = fmaf(p0.x, v0, acc);
        acc = fmaf(p1.x, v1, acc);
        acc = fmaf(p2.x, v2, acc);
        acc = fmaf(p3.x, v3, acc);
      }
      for (; i < cnt; ++i) {
        float2 pr = Pair[i];
        acc = fmaf(pr.x, Vbh[(size_t)__float_as_int(pr.y)*Dn + lane], acc);
      }
    } else {
      // tie-overflow fallback (rare): rewrite full weight row from ordinals
      // (repairs any tail clobbered by Pair writes), then walk all keys.
#pragma unroll
      for (int i = 0; i < 16; ++i)
        Ws[r][lane + 64*i] = (u[i] >= thr) ? __expf(invOrd(u[i]) - m) : 0.f;
      for (int j = 0; j < 1024; ++j) {
        float wgt = Ws[r][j];
        if (wgt != 0.f) acc = fmaf(wgt, Vbh[(size_t)j*Dn + lane], acc);
      }
    }

    int b = bh / Hn, h = bh - b*Hn;
    out[((size_t)(b*Nn + qbase + r))*Cn + h*Dn + lane] = acc * (1.0f / Z);
  }
}

extern "C" void kernel_launch(void* const* d_in, const int* in_sizes, int n_in,
                              void* d_out, int out_size, void* d_ws, size_t ws_size,
                              hipStream_t stream) {
  const float* x      = (const float*)d_in[0];
  const float* qkv_w  = (const float*)d_in[1];
  const float* qkv_b  = (const float*)d_in[2];
  const float* proj_w = (const float*)d_in[3];
  const float* proj_b = (const float*)d_in[4];
  const int*   kptr   = (const int*)d_in[5];

  float* ws  = (float*)d_ws;
  const size_t sz = (size_t)Bn * Hn * Nn * Dn;   // 6291456 elements
  float* qbuf = ws;
  float* kbuf = ws + sz;
  float* vbuf = ws + 2*sz;
  float* att  = ws + 3*sz;                       // (B,N,C)
  float* outp = (float*)d_out;

  qkv_gemm<<<dim3(18*64), 256, 0, stream>>>(x, qkv_w, qkv_b, qbuf, kbuf, vbuf);
  attn_kernel<<<dim3(Bn*Hn*(Nn/16)), 512, 0, stream>>>(qbuf, kbuf, vbuf, kptr, att);
  proj_gemm<<<dim3(6*64), 256, 0, stream>>>(att, proj_w, proj_b, outp);
}

// Round 9
// 838.478 us; speedup vs baseline: 2.5482x; 1.2716x over previous
//
#include <hip/hip_runtime.h>

constexpr int Bn = 8, Nn = 1024, Cn = 768, Hn = 12, Dn = 64;

typedef _Float16 f16x4 __attribute__((ext_vector_type(4)));
typedef _Float16 f16x8 __attribute__((ext_vector_type(8)));
typedef float    f32x4v __attribute__((ext_vector_type(4)));

__device__ __forceinline__ unsigned toOrd(float f) {
  unsigned u = __float_as_uint(f);
  return (u & 0x80000000u) ? ~u : (u | 0x80000000u);
}
__device__ __forceinline__ float invOrd(unsigned v) {
  unsigned b = (v & 0x80000000u) ? (v & 0x7FFFFFFFu) : ~v;
  return __uint_as_float(b);
}

// ---- wave64 reductions via DPP (pure VALU: no LDS, no SALU hazards) --------
__device__ __forceinline__ int wave_sum_i32(int x) {
  x += __builtin_amdgcn_update_dpp(0, x, 0x111, 0xF, 0xF, false);
  x += __builtin_amdgcn_update_dpp(0, x, 0x112, 0xF, 0xF, false);
  x += __builtin_amdgcn_update_dpp(0, x, 0x114, 0xF, 0xF, false);
  x += __builtin_amdgcn_update_dpp(0, x, 0x118, 0xF, 0xF, false);
  x += __builtin_amdgcn_update_dpp(0, x, 0x142, 0xA, 0xF, false);
  x += __builtin_amdgcn_update_dpp(0, x, 0x143, 0xC, 0xF, false);
  return __builtin_amdgcn_readlane(x, 63);
}
__device__ __forceinline__ float wave_sum_f32(float x) {
  int xi = __float_as_int(x);
  x += __int_as_float(__builtin_amdgcn_update_dpp(0, xi, 0x111, 0xF, 0xF, false)); xi = __float_as_int(x);
  x += __int_as_float(__builtin_amdgcn_update_dpp(0, xi, 0x112, 0xF, 0xF, false)); xi = __float_as_int(x);
  x += __int_as_float(__builtin_amdgcn_update_dpp(0, xi, 0x114, 0xF, 0xF, false)); xi = __float_as_int(x);
  x += __int_as_float(__builtin_amdgcn_update_dpp(0, xi, 0x118, 0xF, 0xF, false)); xi = __float_as_int(x);
  x += __int_as_float(__builtin_amdgcn_update_dpp(0, xi, 0x142, 0xA, 0xF, false)); xi = __float_as_int(x);
  x += __int_as_float(__builtin_amdgcn_update_dpp(0, xi, 0x143, 0xC, 0xF, false));
  return __int_as_float(__builtin_amdgcn_readlane(__float_as_int(x), 63));
}
__device__ __forceinline__ unsigned wave_max_u32(unsigned x) {
  int xi = (int)x;              // old = self: identity under max
  x = max(x, (unsigned)__builtin_amdgcn_update_dpp(xi, xi, 0x111, 0xF, 0xF, false)); xi = (int)x;
  x = max(x, (unsigned)__builtin_amdgcn_update_dpp(xi, xi, 0x112, 0xF, 0xF, false)); xi = (int)x;
  x = max(x, (unsigned)__builtin_amdgcn_update_dpp(xi, xi, 0x114, 0xF, 0xF, false)); xi = (int)x;
  x = max(x, (unsigned)__builtin_amdgcn_update_dpp(xi, xi, 0x118, 0xF, 0xF, false)); xi = (int)x;
  x = max(x, (unsigned)__builtin_amdgcn_update_dpp(xi, xi, 0x142, 0xA, 0xF, false)); xi = (int)x;
  x = max(x, (unsigned)__builtin_amdgcn_update_dpp(xi, xi, 0x143, 0xC, 0xF, false));
  return (unsigned)__builtin_amdgcn_readlane((int)x, 63);
}
__device__ __forceinline__ unsigned wave_min_u32(unsigned x) {
  int xi = (int)x;              // old = self: identity under min
  x = min(x, (unsigned)__builtin_amdgcn_update_dpp(xi, xi, 0x111, 0xF, 0xF, false)); xi = (int)x;
  x = min(x, (unsigned)__builtin_amdgcn_update_dpp(xi, xi, 0x112, 0xF, 0xF, false)); xi = (int)x;
  x = min(x, (unsigned)__builtin_amdgcn_update_dpp(xi, xi, 0x114, 0xF, 0xF, false)); xi = (int)x;
  x = min(x, (unsigned)__builtin_amdgcn_update_dpp(xi, xi, 0x118, 0xF, 0xF, false)); xi = (int)x;
  x = min(x, (unsigned)__builtin_amdgcn_update_dpp(xi, xi, 0x142, 0xA, 0xF, false)); xi = (int)x;
  x = min(x, (unsigned)__builtin_amdgcn_update_dpp(xi, xi, 0x143, 0xC, 0xF, false));
  return (unsigned)__builtin_amdgcn_readlane((int)x, 63);
}

// ------- QK GEMM (fp32, bit-identical to R6 path; n-tiles 0..11 only) -------
__global__ __launch_bounds__(256, 4) void qk_gemm(
    const float* __restrict__ X, const float* __restrict__ Wm,
    const float* __restrict__ bias,
    float* __restrict__ qb, float* __restrict__ kb)
{
  constexpr int BK = 16, LD = 132;
  __shared__ float As[BK][LD];
  __shared__ float Bs[BK][LD];
  int t = threadIdx.x;
  int mt = blockIdx.x & 63;         // 64 m-tiles
  int nt = blockIdx.x >> 6;         // 12 n-tiles (q,k cols only)
  int m0 = mt * 128, n0 = nt * 128;
  int sr = t >> 1;                  // staging row 0..127
  int sk = (t & 1) * 8;             // staging k 0 or 8
  const float* Ap = X  + (size_t)(m0 + sr) * Cn + sk;
  const float* Bp = Wm + (size_t)(n0 + sr) * Cn + sk;
  int tm = t >> 4, tn = t & 15;
  float acc[8][8] = {};
  for (int k0 = 0; k0 < Cn; k0 += BK) {
    float4 a0 = *(const float4*)(Ap + k0);
    float4 a1 = *(const float4*)(Ap + k0 + 4);
    float4 b0 = *(const float4*)(Bp + k0);
    float4 b1 = *(const float4*)(Bp + k0 + 4);
    __syncthreads();
    As[sk+0][sr]=a0.x; As[sk+1][sr]=a0.y; As[sk+2][sr]=a0.z; As[sk+3][sr]=a0.w;
    As[sk+4][sr]=a1.x; As[sk+5][sr]=a1.y; As[sk+6][sr]=a1.z; As[sk+7][sr]=a1.w;
    Bs[sk+0][sr]=b0.x; Bs[sk+1][sr]=b0.y; Bs[sk+2][sr]=b0.z; Bs[sk+3][sr]=b0.w;
    Bs[sk+4][sr]=b1.x; Bs[sk+5][sr]=b1.y; Bs[sk+6][sr]=b1.z; Bs[sk+7][sr]=b1.w;
    __syncthreads();
#pragma unroll
    for (int kk = 0; kk < BK; ++kk) {
      float4 x0 = *(const float4*)(&As[kk][tm*8]);
      float4 x1 = *(const float4*)(&As[kk][tm*8+4]);
      float4 y0 = *(const float4*)(&Bs[kk][tn*8]);
      float4 y1 = *(const float4*)(&Bs[kk][tn*8+4]);
      float av[8] = {x0.x,x0.y,x0.z,x0.w,x1.x,x1.y,x1.z,x1.w};
      float bv[8] = {y0.x,y0.y,y0.z,y0.w,y1.x,y1.y,y1.z,y1.w};
#pragma unroll
      for (int i = 0; i < 8; ++i)
#pragma unroll
        for (int j = 0; j < 8; ++j) acc[i][j] = fmaf(av[i], bv[j], acc[i][j]);
    }
  }
  int c0 = n0 + tn*8;
  int which = c0 / Cn;              // 0 or 1 here
  int rem0 = c0 - which*Cn;
  float* dst = which == 0 ? qb : kb;
  float sc = which == 0 ? 0.125f : 1.0f;   // q pre-scaled by d^-0.5
  float4 bs0 = *(const float4*)(bias + c0);
  float4 bs1 = *(const float4*)(bias + c0 + 4);
  int h0 = rem0 >> 6, dd0 = rem0 & 63;
#pragma unroll
  for (int i = 0; i < 8; ++i) {
    int mrow = m0 + tm*8 + i;
    int bbi = mrow >> 10, n = mrow & 1023;
    size_t base = (((size_t)(bbi*Hn + h0))*Nn + n)*Dn + dd0;
    float4 o0, o1;
    o0.x=(acc[i][0]+bs0.x)*sc; o0.y=(acc[i][1]+bs0.y)*sc; o0.z=(acc[i][2]+bs0.z)*sc; o0.w=(acc[i][3]+bs0.w)*sc;
    o1.x=(acc[i][4]+bs1.x)*sc; o1.y=(acc[i][5]+bs1.y)*sc; o1.z=(acc[i][6]+bs1.z)*sc; o1.w=(acc[i][7]+bs1.w)*sc;
    *(float4*)(dst + base)     = o0;
    *(float4*)(dst + base + 4) = o1;
  }
}

// ------- fp16 MFMA GEMM core (M128 x N64 tile, 4 waves, 16x16x32_f16) -------
// C[m][n] = sum_k A[m][k] * W[n][k]; epilogue(gm, gn, val) stores.
// a/b frag layout: X[idx = lane&15][k = (lane>>4)*8 + j]; C/D: col=lane&15,
// row=quad*4+reg (m89-verified). Single fp16: rel err ~2^-10 -> only for
// selection-free outputs (v, proj).
template <typename Epi>
__device__ __forceinline__ void mfma_gemm_body(
    const float* __restrict__ Xp, const float* __restrict__ Wp, Epi epi)
{
  constexpr int LDH = 40; // fp16 row stride: 80B, 16B-aligned, 2-way banks
  __shared__ _Float16 Ah[128*LDH];
  __shared__ _Float16 Bh[64*LDH];
  int t = threadIdx.x;
  int wv = t >> 6, lane = t & 63;
  int quad = lane >> 4, l16 = lane & 15;
  int mt = blockIdx.x & 63, nt = blockIdx.x >> 6;
  int m0 = mt*128, n0 = nt*64;
  f32x4v acc[2][4] = {};
  for (int k0 = 0; k0 < 768; k0 += 32) {
    float4 av[4]; float4 bv[2];
#pragma unroll
    for (int i = 0; i < 4; ++i) {
      int q = t + i*256;   // A tile: 128 rows x 32 k = 1024 float4 loads
      av[i] = *(const float4*)(Xp + (size_t)(m0+(q>>3))*768 + k0 + (q&7)*4);
    }
#pragma unroll
    for (int i = 0; i < 2; ++i) {
      int q = t + i*256;   // B tile: 64 rows x 32 k = 512 float4 loads
      bv[i] = *(const float4*)(Wp + (size_t)(n0+(q>>3))*768 + k0 + (q&7)*4);
    }
    __syncthreads();
#pragma unroll
    for (int i = 0; i < 4; ++i) {
      int q = t + i*256;
      f16x4 h; h[0]=(_Float16)av[i].x; h[1]=(_Float16)av[i].y;
               h[2]=(_Float16)av[i].z; h[3]=(_Float16)av[i].w;
      *(f16x4*)(&Ah[(q>>3)*LDH + (q&7)*4]) = h;
    }
#pragma unroll
    for (int i = 0; i < 2; ++i) {
      int q = t + i*256;
      f16x4 h; h[0]=(_Float16)bv[i].x; h[1]=(_Float16)bv[i].y;
               h[2]=(_Float16)bv[i].z; h[3]=(_Float16)bv[i].w;
      *(f16x4*)(&Bh[(q>>3)*LDH + (q&7)*4]) = h;
    }
    __syncthreads();
    f16x8 bf[4], af;
#pragma unroll
    for (int ni = 0; ni < 4; ++ni)
      bf[ni] = *(f16x8*)(&Bh[(ni*16+l16)*LDH + quad*8]);
#pragma unroll
    for (int mi = 0; mi < 2; ++mi) {
      af = *(f16x8*)(&Ah[(wv*32+mi*16+l16)*LDH + quad*8]);
#pragma unroll
      for (int ni = 0; ni < 4; ++ni)
        acc[mi][ni] = __builtin_amdgcn_mfma_f32_16x16x32_f16(af, bf[ni], acc[mi][ni], 0, 0, 0);
    }
  }
#pragma unroll
  for (int mi = 0; mi < 2; ++mi)
#pragma unroll
    for (int ni = 0; ni < 4; ++ni)
#pragma unroll
      for (int r = 0; r < 4; ++r) {
        int gm = m0 + wv*32 + mi*16 + quad*4 + r;
        int gn = n0 + ni*16 + l16;
        epi(gm, gn, acc[mi][ni][r]);
      }
}

// v = x @ Wv^T + bv, scattered to (B,H,N,d)
__global__ __launch_bounds__(256) void v_gemm_mfma(
    const float* __restrict__ Xp, const float* __restrict__ Wp,
    const float* __restrict__ bias, float* __restrict__ vb)
{
  mfma_gemm_body(Xp, Wp, [=](int gm, int gn, float val) {
    int h = gn >> 6;
    int dd = gn & 63;
    int bbi = gm >> 10;
    int nn = gm & 1023;
    vb[(((size_t)(bbi*Hn + h))*Nn + nn)*Dn + dd] = val + bias[gn];
  });
}

// out = att @ Wp^T + bp (row-major, final output)
__global__ __launch_bounds__(256) void proj_mfma(
    const float* __restrict__ Xp, const float* __restrict__ Wp,
    const float* __restrict__ bias, float* __restrict__ Out)
{
  mfma_gemm_body(Xp, Wp, [=](int gm, int gn, float val) {
    Out[(size_t)gm*768 + gn] = val + bias[gn];
  });
}

// ---------------- Attention: UNCHANGED from R6 ------------------------------
__global__ __launch_bounds__(512, 4) void attn_kernel(
    const float* __restrict__ qB, const float* __restrict__ kB,
    const float* __restrict__ vB, const int* __restrict__ kptr,
    float* __restrict__ out)
{
  constexpr int G = 16, CAP = 128;
  __shared__ float  Ws[G][1024];     // 64 KB; tail of each row reused for pairs
  __shared__ float4 Qs[G][16];       // 4 KB

  int t = threadIdx.x;
  int bh = blockIdx.x >> 6;          // 0..95  (b*12+h)
  int qg = blockIdx.x & 63;
  int qbase = qg * G;
  const float* Kbh = kB + (size_t)bh * Nn * Dn;
  const float* Vbh = vB + (size_t)bh * Nn * Dn;
  const float* Qbh = qB + (size_t)bh * Nn * Dn;

  for (int i = t; i < G*16; i += 512) {
    int r = i >> 4, d4 = i & 15;
    Qs[r][d4] = ((const float4*)(Qbh + (size_t)(qbase + r) * Dn))[d4];
  }
  __syncthreads();

  {
    const float4* K0 = (const float4*)(Kbh + (size_t)t * Dn);
    const float4* K1 = (const float4*)(Kbh + (size_t)(t + 512) * Dn);
    float acc0[G], acc1[G];
#pragma unroll
    for (int r = 0; r < G; ++r) { acc0[r] = 0.f; acc1[r] = 0.f; }
#pragma unroll
    for (int d4 = 0; d4 < 16; ++d4) {
      float4 k0 = K0[d4], k1 = K1[d4];
#pragma unroll
      for (int r = 0; r < G; ++r) {
        float4 q4 = Qs[r][d4];
        acc0[r] = fmaf(q4.x,k0.x, fmaf(q4.y,k0.y, fmaf(q4.z,k0.z, fmaf(q4.w,k0.w, acc0[r]))));
        acc1[r] = fmaf(q4.x,k1.x, fmaf(q4.y,k1.y, fmaf(q4.z,k1.z, fmaf(q4.w,k1.w, acc1[r]))));
      }
    }
#pragma unroll
    for (int r = 0; r < G; ++r) { Ws[r][t] = acc0[r]; Ws[r][t + 512] = acc1[r]; }
  }
  __syncthreads();

  int w = t >> 6, lane = t & 63;
  int kval = *kptr;
  bool doSel = (kval > 0 && kval < Nn);

  for (int p = 0; p < 2; ++p) {
    int r = w * 2 + p;
    unsigned u[16];
#pragma unroll
    for (int i = 0; i < 16; ++i)
      u[i] = toOrd(Ws[r][lane + 64*i]);

    unsigned mu = u[0];
#pragma unroll
    for (int i = 1; i < 16; ++i) mu = max(mu, u[i]);
    float m = invOrd(wave_max_u32(mu));

    unsigned thr = 0u;
    if (doSel) {
      unsigned res = 0u;
      for (int bit = 31; bit >= 0; --bit) {
        unsigned cand = res | (1u << bit);
        int c = 0;
#pragma unroll
        for (int i = 0; i < 16; ++i) c += (u[i] >= cand) ? 1 : 0;
        int ct = wave_sum_i32(c);
        if (ct == kval) {
          unsigned mn = 0xFFFFFFFFu;
#pragma unroll
          for (int i = 0; i < 16; ++i)
            if (u[i] >= cand && u[i] < mn) mn = u[i];
          res = wave_min_u32(mn);
          break;
        }
        if (ct > kval) res = cand;
      }
      thr = res;
    }

    float2* Pair = (float2*)&Ws[r][1024 - 2*CAP];
    float Zl = 0.f;
    int cnt = 0;
#pragma unroll
    for (int i = 0; i < 16; ++i) {
      bool keep = (u[i] >= thr);
      unsigned long long msk = __ballot(keep);
      if (keep) {
        float wgt = __expf(invOrd(u[i]) - m);
        Zl += wgt;
        int pos = cnt + __popcll(msk & ((1ull << lane) - 1ull));
        if (pos < CAP) {
          float2 pr; pr.x = wgt; pr.y = __int_as_float(lane + 64*i);
          Pair[pos] = pr;
        }
      }
      cnt += __popcll(msk);
    }
    float Z = wave_sum_f32(Zl);

    float acc = 0.f;
    if (cnt <= CAP) {
      int i = 0;
      for (; i + 4 <= cnt; i += 4) {
        float2 p0 = Pair[i],   p1 = Pair[i+1];
        float2 p2 = Pair[i+2], p3 = Pair[i+3];
        int j0 = __float_as_int(p0.y), j1 = __float_as_int(p1.y);
        int j2 = __float_as_int(p2.y), j3 = __float_as_int(p3.y);
        float v0 = Vbh[(size_t)j0*Dn + lane];
        float v1 = Vbh[(size_t)j1*Dn + lane];
        float v2 = Vbh[(size_t)j2*Dn + lane];
        float v3 = Vbh[(size_t)j3*Dn + lane];
        acc = fmaf(p0.x, v0, acc);
        acc = fmaf(p1.x, v1, acc);
        acc = fmaf(p2.x, v2, acc);
        acc = fmaf(p3.x, v3, acc);
      }
      for (; i < cnt; ++i) {
        float2 pr = Pair[i];
        acc = fmaf(pr.x, Vbh[(size_t)__float_as_int(pr.y)*Dn + lane], acc);
      }
    } else {
#pragma unroll
      for (int i = 0; i < 16; ++i)
        Ws[r][lane + 64*i] = (u[i] >= thr) ? __expf(invOrd(u[i]) - m) : 0.f;
      for (int j = 0; j < 1024; ++j) {
        float wgt = Ws[r][j];
        if (wgt != 0.f) acc = fmaf(wgt, Vbh[(size_t)j*Dn + lane], acc);
      }
    }

    int b = bh / Hn, h = bh - b*Hn;
    out[((size_t)(b*Nn + qbase + r))*Cn + h*Dn + lane] = acc * (1.0f / Z);
  }
}

extern "C" void kernel_launch(void* const* d_in, const int* in_sizes, int n_in,
                              void* d_out, int out_size, void* d_ws, size_t ws_size,
                              hipStream_t stream) {
  const float* x      = (const float*)d_in[0];
  const float* qkv_w  = (const float*)d_in[1];
  const float* qkv_b  = (const float*)d_in[2];
  const float* proj_w = (const float*)d_in[3];
  const float* proj_b = (const float*)d_in[4];
  const int*   kptr   = (const int*)d_in[5];

  float* ws  = (float*)d_ws;
  const size_t sz = (size_t)Bn * Hn * Nn * Dn;   // 6291456 elements
  float* qbuf = ws;
  float* kbuf = ws + sz;
  float* vbuf = ws + 2*sz;
  float* att  = ws + 3*sz;                       // (B,N,C)
  float* outp = (float*)d_out;

  qk_gemm<<<dim3(12*64), 256, 0, stream>>>(x, qkv_w, qkv_b, qbuf, kbuf);
  v_gemm_mfma<<<dim3(12*64), 256, 0, stream>>>(x, qkv_w + (size_t)1536*Cn,
                                               qkv_b + 1536, vbuf);
  attn_kernel<<<dim3(Bn*Hn*(Nn/16)), 512, 0, stream>>>(qbuf, kbuf, vbuf, kptr, att);
  proj_mfma<<<dim3(12*64), 256, 0, stream>>>(att, proj_w, proj_b, outp);
}